// Round 13
// baseline (1949.476 us; speedup 1.0000x reference)
//
#include <hip/hip_runtime.h>
#include <math.h>

// Problem: MPMatcher  S=6, B=16, L=8, M=256, K=128
// Phase 1 (PASSING, DO NOT TOUCH): cost f32, ocml logf, *(1/6) reciprocal mean.
// Phase 2: reference's buggy greedy walk, f64-exact. R12: dummy-class split.
//   Free-dummy candidates are (0-u)-v_r with v_r frozen while free and u
//   wave-uniform -> dummy argmin = argmax v_r (first-j on ties), independent
//   of u and of the row load. Maintain (jdA,vA) + prefetched (jdB,vB) with
//   rows preloaded; per-iter dummy side = 2 uniform f64 ops. Ladder covers
//   only the 128 real cols. Dummy-win iterations skip load wait + extraction.

#define S_ 6
#define B_ 16
#define L_ 8
#define M_ 256
#define K_ 128

// ---------------------------------------------------------------- cost kernel
__global__ void cost_kernel(const float* __restrict__ mp,   // (6,16,8,256,2)
                            const float* __restrict__ mv,   // (6,16,256,1)
                            const float* __restrict__ gt,   // (6,16,128,2)
                            const float* __restrict__ gv,   // (6,16,128,1)
                            float* __restrict__ cost)       // (16,256,128)
{
#pragma clang fp contract(off)
    const int b = blockIdx.x;
    const int m = blockIdx.y;
    const int k = threadIdx.x;

    float accS = 0.0f;
    for (int s = 0; s < S_; ++s) {
        const int sb = s * B_ + b;
        const float gx = gt[(sb * K_ + k) * 2 + 0];
        const float gy = gt[(sb * K_ + k) * 2 + 1];
        float accL = 0.0f;
#pragma unroll
        for (int l = 0; l < L_; ++l) {
            const int base = ((sb * L_ + l) * M_ + m) * 2;
            const float dx = fabsf(mp[base + 0] - gx);
            const float dy = fabsf(mp[base + 1] - gy);
            const float diff = dx + dy;
            const float dl = (float)(L_ - (l + 1)) * 0.05f;
            const float t = diff - dl;
            accL += fmaxf(t, 0.0f);
        }
        const float meanL = accL * 0.125f;
        const float mvv = mv[sb * M_ + m];
        const float gtv = gv[sb * K_ + k];
        const float lp = -logf(mvv);
        const float ln = -logf(1.0f - mvv);
        const float val = (gtv != 0.0f) ? (5.0f * meanL + lp) : ln;
        accS += val;
    }
    cost[(b * M_ + m) * K_ + k] = accS * (1.0f / 6.0f);
}

// --------------------------------------------------------------- bit helpers
__device__ __forceinline__ double bits2d(int lo, int hi) {
    const unsigned long long u =
        ((unsigned long long)(unsigned)hi << 32) | (unsigned)lo;
    return __longlong_as_double((long long)u);
}
__device__ __forceinline__ void d2bits(double d, int& lo, int& hi) {
    const unsigned long long u = (unsigned long long)__double_as_longlong(d);
    lo = (int)(u & 0xffffffffull);
    hi = (int)(u >> 32);
}

// Lexicographic (max v, min j) wave reduction over each lane's two dummy
// slots. Exact total order -> any covering tree is exact (R8-proven ladder).
__device__ __forceinline__ void dummy_sel(double v2, double v3, bool e2, bool e3,
                                          int lane, int& jd, double& vs) {
    const double NINF = -__builtin_inf();
    double bv = e2 ? v2 : NINF;
    int bj = e2 ? (2 * lane + 129) : 0x7fffffff;
    if (e3 && (v3 > bv)) { bv = v3; bj = 2 * lane + 130; }  // tie keeps slot2 (smaller j)
    int lo, hi; d2bits(bv, lo, hi);
    int idx = bj;
#define SEL_STAGE(CTRL, RM)                                                      \
    {                                                                            \
        const int nlo = __builtin_amdgcn_update_dpp(lo, lo, CTRL, RM, 0xf, false);   \
        const int nhi = __builtin_amdgcn_update_dpp(hi, hi, CTRL, RM, 0xf, false);   \
        const int nix = __builtin_amdgcn_update_dpp(idx, idx, CTRL, RM, 0xf, false); \
        const double nv = bits2d(nlo, nhi);                                      \
        const double cv = bits2d(lo, hi);                                        \
        const bool take = (nv > cv) || (nv == cv && nix < idx);                  \
        lo = take ? nlo : lo; hi = take ? nhi : hi; idx = take ? nix : idx;      \
    }
    SEL_STAGE(0x111, 0xf)   // row_shr:1
    SEL_STAGE(0x112, 0xf)   // row_shr:2
    SEL_STAGE(0x114, 0xf)   // row_shr:4
    SEL_STAGE(0x118, 0xf)   // row_shr:8
    SEL_STAGE(0x142, 0xa)   // row_bcast:15
    SEL_STAGE(0x143, 0xc)   // row_bcast:31
#undef SEL_STAGE
    jd = __builtin_amdgcn_readlane(idx, 63);
    vs = bits2d(__builtin_amdgcn_readlane(lo, 63),
                __builtin_amdgcn_readlane(hi, 63));   // -INF if pool empty
}

// ------------------------------------------------------------- matcher kernel
// One wave per batch. Lane owns real cols j=2*lane+1, 2*lane+2 (slots 0,1)
// and dummy cols j=2*lane+129, 2*lane+130 (slots 2,3).
__global__ __launch_bounds__(64, 1) void match_kernel(const float* __restrict__ cost,
                                                      int* __restrict__ out)
{
#pragma clang fp contract(off)
    const int b = blockIdx.x;
    const int lane = threadIdx.x;   // 0..63
    const float* C = cost + (size_t)b * M_ * K_;
    const double INF = __builtin_inf();
    const int BIG = 0x7fffffff;

    __shared__ float  C_lds[M_ * K_];   // 128 KB cost slab (row-major, = global)
    __shared__ double u_lds[257];       // u[0..256], 1-based rows
    __shared__ int    p_lds[257];       // p[j] = row matched to col j; 0 = free

    for (int t = lane; t < (M_ * K_) / 4; t += 64)
        ((float4*)C_lds)[t] = ((const float4*)C)[t];

    // rows 1..128 pre-matched to dummy cols 129..256 (exact, proven R8)
    for (int t = lane; t < 257; t += 64) {
        u_lds[t] = 0.0;
        p_lds[t] = (t >= 129) ? (t - 128) : 0;
    }
    __syncthreads();

    double v0 = 0.0, v1 = 0.0, v2 = 0.0, v3 = 0.0;  // column potentials

    for (int i = 129; i <= 256; ++i) {
        // ---- row start: snapshots (validity proven R8-R11: p static in-walk;
        // a free col's row-u is first updated only after that col is used).
        int used = 0;
        const int pj0 = p_lds[2 * lane + 1];
        const int pj1 = p_lds[2 * lane + 2];
        double ur0 = u_lds[pj0], ur1 = u_lds[pj1];
        double ur2 = u_lds[2 * lane + 1];        // p[dummy 2l+129] == 2l+1 forever
        double ur3 = u_lds[2 * lane + 2];
        const double up0 = ur0, up1 = ur1, up2 = ur2, up3 = ur3;

        // walk-start dummy selection: jdA = argmax v (first-j), jdB = next
        int jdA, jdB; double vAs, vBs;
        dummy_sel(v2, v3, true, true, lane, jdA, vAs);
        {
            const bool e2 = (jdA != 2 * lane + 129);
            const bool e3 = (jdA != 2 * lane + 130);
            dummy_sel(v2, v3, e2, e3, lane, jdB, vBs);
        }
        // row loads: current row + both dummy-successor rows
        float2 cc  = *(const float2*)(C_lds + (i - 1) * K_ + 2 * lane);
        float2 ccA = *(const float2*)(C_lds + ((jdA == BIG ? 129 : jdA) - 129) * K_ + 2 * lane);
        float2 ccB = *(const float2*)(C_lds + ((jdB == BIG ? 129 : jdB) - 129) * K_ + 2 * lane);

        double u_i0 = 0.0;
        int j1 = 0;
        double usum = 0.0;

        for (;;) {
            // real candidates (exact ref op order, f64)
            double cd0 = ((double)cc.x - u_i0) - v0;
            double cd1 = ((double)cc.y - u_i0) - v1;
            if (used & 1) cd0 = INF;
            if (used & 2) cd1 = INF;
            double bv = fmin(cd0, cd1);

            // wave value-min over the 128 real cols (DPP ladder, R9-proven)
            int lo, hi; d2bits(bv, lo, hi);
#define MIN_STAGE(CTRL, RM)                                                      \
            {                                                                    \
                const int nlo = __builtin_amdgcn_update_dpp(lo, lo, CTRL, RM, 0xf, false); \
                const int nhi = __builtin_amdgcn_update_dpp(hi, hi, CTRL, RM, 0xf, false); \
                const double mv2 = fmin(bits2d(lo, hi), bits2d(nlo, nhi));       \
                d2bits(mv2, lo, hi);                                             \
            }
            MIN_STAGE(0x111, 0xf)
            MIN_STAGE(0x112, 0xf)
            MIN_STAGE(0x114, 0xf)
            MIN_STAGE(0x118, 0xf)
            MIN_STAGE(0x142, 0xa)
            MIN_STAGE(0x143, 0xc)
#undef MIN_STAGE
            const double Rmin = bits2d(__builtin_amdgcn_readlane(lo, 63),
                                       __builtin_amdgcn_readlane(hi, 63));

            // dummy-class min: (0 - u) - v_jdA  (ref op order for col jdA;
            // equals min over free dummies since fl is monotone in v)
            const double Dmin = (0.0 - u_i0) - vAs;   // +INF when pool empty

            const double delta = fmin(Rmin, Dmin);
            const bool realw = (Rmin <= Dmin);   // tie -> real class (smaller j)

            // potential updates (ref order; jdA not yet marked -> not updated,
            // matching ref's mark-at-next-iteration-top semantics)
            usum += delta;
            if (used & 1) { ur0 += delta; v0 -= delta; }
            if (used & 2) { ur1 += delta; v1 -= delta; }
            if (used & 4) { ur2 += delta; v2 -= delta; }
            if (used & 8) { ur3 += delta; v3 -= delta; }

            if (realw) {
                // first-index among real achievers (cd == delta)
                int jr = BIG;
                if (cd1 == delta) jr = 2 * lane + 2;
                if (cd0 == delta) jr = 2 * lane + 1;
                const unsigned long long bb = __ballot(jr != BIG);
                j1 = __builtin_amdgcn_readlane(jr, (int)__builtin_ctzll(bb));
                const int ol = (j1 - 1) >> 1, sl = (j1 - 1) & 1;
                const int psel = sl ? pj1 : pj0;
                const int i0n = __builtin_amdgcn_readlane(psel, ol);
                if (i0n == 0) break;             // free real col -> augment
                const double usel = sl ? up1 : up0;
                int ulo, uhi; d2bits(usel, ulo, uhi);
                u_i0 = bits2d(__builtin_amdgcn_readlane(ulo, ol),
                              __builtin_amdgcn_readlane(uhi, ol));
                if (lane == ol) used |= (1 << sl);
                cc = *(const float2*)(C_lds + (i0n - 1) * K_ + 2 * lane);
            } else {
                j1 = jdA;                         // next row = jdA-128 (1..128)
                const int ol = (jdA - 129) >> 1, sl = 2 + ((jdA - 129) & 1);
                const double usel = (sl == 2) ? up2 : up3;
                int ulo, uhi; d2bits(usel, ulo, uhi);
                u_i0 = bits2d(__builtin_amdgcn_readlane(ulo, ol),
                              __builtin_amdgcn_readlane(uhi, ol));
                if (lane == ol) used |= (1 << sl);   // mark before jdB recompute
                cc = ccA; ccA = ccB; jdA = jdB; vAs = vBs;
                // refill successor (off critical path; needed 2 wins later)
                const bool e2 = !(used & 4) && (jdA != 2 * lane + 129);
                const bool e3 = !(used & 8) && (jdA != 2 * lane + 130);
                dummy_sel(v2, v3, e2, e3, lane, jdB, vBs);
                ccB = *(const float2*)(C_lds + ((jdB == BIG ? 129 : jdB) - 129) * K_ + 2 * lane);
            }
        }

        // ---- commit: marked slots write their running u; lane 0 augments
        __syncthreads();
        if (used & 1) u_lds[pj0] = ur0;
        if (used & 2) u_lds[pj1] = ur1;
        if (used & 4) u_lds[2 * lane + 1] = ur2;
        if (used & 8) u_lds[2 * lane + 2] = ur3;
        if (lane == 0) { p_lds[j1] = i; u_lds[i] = usum; }
        __syncthreads();
    }

    // out[b][k] = p[k+1] - 1 for the K real columns
    for (int j = lane; j < K_; j += 64)
        out[b * K_ + j] = p_lds[j + 1] - 1;
}

// ------------------------------------------------------------------- launcher
extern "C" void kernel_launch(void* const* d_in, const int* in_sizes, int n_in,
                              void* d_out, int out_size, void* d_ws, size_t ws_size,
                              hipStream_t stream) {
    const float* mp = (const float*)d_in[0];   // meta_points
    const float* mv = (const float*)d_in[1];   // meta_visibles
    /* d_in[2] covisibles: unused by reference */
    const float* gt = (const float*)d_in[3];   // gtpoints
    const float* gv = (const float*)d_in[4];   // gtvisibles
    int* out = (int*)d_out;                    // int32 assignment indices
    float* cost = (float*)d_ws;                // 16*256*128 fp32 = 2 MB

    dim3 gridA(B_, M_);
    cost_kernel<<<gridA, K_, 0, stream>>>(mp, mv, gt, gv, cost);
    match_kernel<<<B_, 64, 0, stream>>>(cost, out);
}